// Round 1
// baseline (2706.237 us; speedup 1.0000x reference)
//
#include <hip/hip_runtime.h>
#include <math.h>

#define BATCH 8
#define HH 1024
#define WW 1024
#define CC 3
#define MTOT (HH*WW*CC)          // 3145728 per batch
#define RSEL 1572864u            // ceil(M/2)
#define NBIN 65536

// ---- ws layout (bytes) ----
// [0, 2MB)        hist1  : BATCH * 65536 u32
// [2MB, 4MB)      hist2  : BATCH * 65536 u32
// [4MB + 0)       cand   : BATCH u32
// [4MB + 64)      base   : BATCH u32
// [4MB + 128)     thr    : BATCH u32
// [4MB + 192)     norm   : 1 float
#define WS_HIST1_OFF   0
#define WS_HIST2_OFF   (2u*1024u*1024u)
#define WS_CAND_OFF    (4u*1024u*1024u)
#define WS_BASE_OFF    (4u*1024u*1024u + 64u)
#define WS_THR_OFF     (4u*1024u*1024u + 128u)
#define WS_NORM_OFF    (4u*1024u*1024u + 192u)
#define WS_ZERO_BYTES  (4u*1024u*1024u + 256u)

__device__ __forceinline__ unsigned int fmap(float x) {
    unsigned int b = __float_as_uint(x);
    return (b & 0x80000000u) ? ~b : (b | 0x80000000u);
}

// ---- Pass 1: histogram of top 16 bits, per batch ----
__global__ void hist_top16(const float* __restrict__ Y, unsigned int* __restrict__ hist) {
    int b = blockIdx.y;
    const float4* Y4 = (const float4*)(Y + (size_t)b * MTOT);
    unsigned int* h = hist + (size_t)b * NBIN;
    int n4 = MTOT / 4;
    for (int i = blockIdx.x * blockDim.x + threadIdx.x; i < n4; i += gridDim.x * blockDim.x) {
        float4 v = Y4[i];
        atomicAdd(&h[fmap(v.x) >> 16], 1u);
        atomicAdd(&h[fmap(v.y) >> 16], 1u);
        atomicAdd(&h[fmap(v.z) >> 16], 1u);
        atomicAdd(&h[fmap(v.w) >> 16], 1u);
    }
}

// ---- Scan 1: descending cumulative over 64K bins, find candidate bin + base rank ----
__global__ void scan_top(const unsigned int* __restrict__ hist,
                         unsigned int* __restrict__ cand,
                         unsigned int* __restrict__ baseCnt) {
    int b = blockIdx.x;
    const unsigned int* h = hist + (size_t)b * NBIN;
    __shared__ unsigned int psum[1024];
    int t = threadIdx.x;
    int dbase = t * 64;                 // descending index chunk
    unsigned int s = 0;
    for (int k = 0; k < 64; k++) s += h[65535 - (dbase + k)];
    psum[t] = s;
    __syncthreads();
    for (int off = 1; off < 1024; off <<= 1) {
        unsigned int v = (t >= off) ? psum[t - off] : 0u;
        __syncthreads();
        psum[t] += v;
        __syncthreads();
    }
    unsigned int incl = psum[t];
    unsigned int excl = incl - s;
    if (excl < RSEL && incl >= RSEL) {
        unsigned int run = excl;
        for (int k = 0; k < 64; k++) {
            unsigned int c = h[65535 - (dbase + k)];
            if (run + c >= RSEL) {
                cand[b] = (unsigned int)(65535 - (dbase + k));
                baseCnt[b] = run;
                break;
            }
            run += c;
        }
    }
}

// ---- Pass 2: histogram of low 16 bits for elements in candidate top bin ----
__global__ void hist_low16(const float* __restrict__ Y,
                           const unsigned int* __restrict__ cand,
                           unsigned int* __restrict__ hist) {
    int b = blockIdx.y;
    unsigned int cb = cand[b];
    const float4* Y4 = (const float4*)(Y + (size_t)b * MTOT);
    unsigned int* h = hist + (size_t)b * NBIN;
    int n4 = MTOT / 4;
    for (int i = blockIdx.x * blockDim.x + threadIdx.x; i < n4; i += gridDim.x * blockDim.x) {
        float4 v = Y4[i];
        unsigned int u;
        u = fmap(v.x); if ((u >> 16) == cb) atomicAdd(&h[u & 0xFFFFu], 1u);
        u = fmap(v.y); if ((u >> 16) == cb) atomicAdd(&h[u & 0xFFFFu], 1u);
        u = fmap(v.z); if ((u >> 16) == cb) atomicAdd(&h[u & 0xFFFFu], 1u);
        u = fmap(v.w); if ((u >> 16) == cb) atomicAdd(&h[u & 0xFFFFu], 1u);
    }
}

// ---- Scan 2: find exact low-16 bin -> full threshold in u-space ----
__global__ void scan_low(const unsigned int* __restrict__ hist,
                         const unsigned int* __restrict__ cand,
                         const unsigned int* __restrict__ baseCnt,
                         unsigned int* __restrict__ thr) {
    int b = blockIdx.x;
    const unsigned int* h = hist + (size_t)b * NBIN;
    unsigned int target = RSEL - baseCnt[b];   // >= 1
    __shared__ unsigned int psum[1024];
    int t = threadIdx.x;
    int dbase = t * 64;
    unsigned int s = 0;
    for (int k = 0; k < 64; k++) s += h[65535 - (dbase + k)];
    psum[t] = s;
    __syncthreads();
    for (int off = 1; off < 1024; off <<= 1) {
        unsigned int v = (t >= off) ? psum[t - off] : 0u;
        __syncthreads();
        psum[t] += v;
        __syncthreads();
    }
    unsigned int incl = psum[t];
    unsigned int excl = incl - s;
    if (excl < target && incl >= target) {
        unsigned int run = excl;
        for (int k = 0; k < 64; k++) {
            unsigned int c = h[65535 - (dbase + k)];
            if (run + c >= target) {
                thr[b] = (cand[b] << 16) | (unsigned int)(65535 - (dbase + k));
                break;
            }
            run += c;
        }
    }
}

// ---- Threshold + NHWC->NCHW transpose. One thread = 4 pixels (w4) x 3 channels ----
__global__ void thresh_kernel(const float* __restrict__ Y,
                              const unsigned int* __restrict__ thr,
                              float* __restrict__ out) {
    int p = blockIdx.x * blockDim.x + threadIdx.x;   // [0, 8*1024*256)
    int w4 = p & 255;            // W/4 = 256
    int h  = (p >> 8) & 1023;
    int b  = p >> 18;
    unsigned int tu = thr[b];
    const float4* src = (const float4*)(Y + ((size_t)((b * HH + h) * WW) + (size_t)w4 * 4) * CC);
    float4 a0 = src[0], a1 = src[1], a2 = src[2];
    float4 r0, r1, r2;
    r0.x = (fmap(a0.x) >= tu) ? 1.f : 0.f;
    r0.y = (fmap(a0.w) >= tu) ? 1.f : 0.f;
    r0.z = (fmap(a1.z) >= tu) ? 1.f : 0.f;
    r0.w = (fmap(a2.y) >= tu) ? 1.f : 0.f;
    r1.x = (fmap(a0.y) >= tu) ? 1.f : 0.f;
    r1.y = (fmap(a1.x) >= tu) ? 1.f : 0.f;
    r1.z = (fmap(a1.w) >= tu) ? 1.f : 0.f;
    r1.w = (fmap(a2.z) >= tu) ? 1.f : 0.f;
    r2.x = (fmap(a0.z) >= tu) ? 1.f : 0.f;
    r2.y = (fmap(a1.y) >= tu) ? 1.f : 0.f;
    r2.z = (fmap(a2.x) >= tu) ? 1.f : 0.f;
    r2.w = (fmap(a2.w) >= tu) ? 1.f : 0.f;
    size_t base = ((size_t)(b * CC) * HH + h) * WW;
    ((float4*)(out + base))[w4]                        = r0;
    ((float4*)(out + base + (size_t)HH * WW))[w4]      = r1;
    ((float4*)(out + base + (size_t)2 * HH * WW))[w4]  = r2;
}

// ---- Z0 norm reduction: sum(abs^2) ----
__global__ void znorm_reduce(const float* __restrict__ zabs, float* __restrict__ acc) {
    int i = blockIdx.x * blockDim.x + threadIdx.x;   // over HH*WW/4 float4
    float s = 0.f;
    if (i < (HH * WW / 4)) {
        float4 v = ((const float4*)zabs)[i];
        s = v.x * v.x + v.y * v.y + v.z * v.z + v.w * v.w;
    }
    for (int off = 32; off > 0; off >>= 1) s += __shfl_down(s, off);
    __shared__ float ls[4];
    if ((threadIdx.x & 63) == 0) ls[threadIdx.x >> 6] = s;
    __syncthreads();
    if (threadIdx.x == 0) atomicAdd(acc, ls[0] + ls[1] + ls[2] + ls[3]);
}

// ---- Z0 write: interleaved complex64 (re,im) or real-only fallback ----
__global__ void zwrite_kernel(const float* __restrict__ zabs,
                              const float* __restrict__ zang,
                              const float* __restrict__ acc,
                              float* __restrict__ outz, int interleaved) {
    int i = blockIdx.x * blockDim.x + threadIdx.x;   // over HH*WW/2 pairs
    if (i >= HH * WW / 2) return;
    float inv = 1.0f / sqrtf(*acc);
    float2 a = ((const float2*)zabs)[i];
    float2 g = ((const float2*)zang)[i];
    float s0, c0, s1, c1;
    __sincosf(g.x, &s0, &c0);
    __sincosf(g.y, &s1, &c1);
    if (interleaved) {
        float4 o;
        o.x = a.x * c0 * inv; o.y = a.x * s0 * inv;
        o.z = a.y * c1 * inv; o.w = a.y * s1 * inv;
        ((float4*)outz)[i] = o;
    } else {
        float2 o;
        o.x = a.x * c0 * inv; o.y = a.y * c1 * inv;
        ((float2*)outz)[i] = o;
    }
}

extern "C" void kernel_launch(void* const* d_in, const int* in_sizes, int n_in,
                              void* d_out, int out_size, void* d_ws, size_t ws_size,
                              hipStream_t stream) {
    const float* Y    = (const float*)d_in[0];
    const float* zabs = (const float*)d_in[1];
    const float* zang = (const float*)d_in[2];
    float* out = (float*)d_out;

    unsigned char* ws = (unsigned char*)d_ws;
    unsigned int* hist1   = (unsigned int*)(ws + WS_HIST1_OFF);
    unsigned int* hist2   = (unsigned int*)(ws + WS_HIST2_OFF);
    unsigned int* cand    = (unsigned int*)(ws + WS_CAND_OFF);
    unsigned int* baseCnt = (unsigned int*)(ws + WS_BASE_OFF);
    unsigned int* thr     = (unsigned int*)(ws + WS_THR_OFF);
    float*        norm    = (float*)(ws + WS_NORM_OFF);

    hipMemsetAsync(d_ws, 0, WS_ZERO_BYTES, stream);

    dim3 hgrid(768, BATCH);
    hist_top16<<<hgrid, 256, 0, stream>>>(Y, hist1);
    scan_top<<<BATCH, 1024, 0, stream>>>(hist1, cand, baseCnt);
    hist_low16<<<hgrid, 256, 0, stream>>>(Y, cand, hist2);
    scan_low<<<BATCH, 1024, 0, stream>>>(hist2, cand, baseCnt, thr);

    // threshold + transpose: B*H*(W/4) = 2097152 threads
    thresh_kernel<<<(BATCH * HH * (WW / 4)) / 256, 256, 0, stream>>>(Y, thr, out);

    // Z0
    znorm_reduce<<<(HH * WW / 4) / 256, 256, 0, stream>>>(zabs, norm);
    size_t zoff = (size_t)BATCH * CC * HH * WW;   // 25165824
    int zfloats = out_size - (int)zoff;
    int interleaved = (zfloats >= 2 * HH * WW) ? 1 : 0;
    zwrite_kernel<<<(HH * WW / 2 + 255) / 256, 256, 0, stream>>>(
        zabs, zang, norm, out + zoff, interleaved);
}

// Round 2
// 255.250 us; speedup vs baseline: 10.6023x; 10.6023x over previous
//
#include <hip/hip_runtime.h>
#include <math.h>

#define BATCH 8
#define HH 1024
#define WW 1024
#define CC 3
#define MTOT (HH*WW*CC)          // 3145728 per batch
#define RSEL 1572864u            // ceil(M/2)
#define CAP  262144u             // compaction buffer capacity per batch

// ---- ws layout (bytes) ----
#define WS_GH1_OFF    0u                    // 8*4096 u32 = 128 KB
#define WS_GH2_OFF    (128u*1024u)          // 8*4096 u32 = 128 KB
#define WS_GH3_OFF    (256u*1024u)          // 8*256 u32  = 8 KB
#define WS_CNT_OFF    (264u*1024u)          // 8 u32
#define WS_CAND1_OFF  (264u*1024u + 64u)
#define WS_BASE1_OFF  (264u*1024u + 128u)
#define WS_CAND2_OFF  (264u*1024u + 192u)
#define WS_BASE2_OFF  (264u*1024u + 256u)
#define WS_THR_OFF    (264u*1024u + 320u)
#define WS_NORM_OFF   (264u*1024u + 384u)
#define WS_ZERO_BYTES (264u*1024u + 448u)
#define WS_BUF_OFF    (1024u*1024u)         // 8 * 256K u32 = 8 MB

__device__ __forceinline__ unsigned int fmap(float x) {
    unsigned int b = __float_as_uint(x);
    return (b & 0x80000000u) ? ~b : (b | 0x80000000u);
}

// ---- Pass 1: top-12-bit histogram, LDS-privatized per block ----
__global__ void hist1_kernel(const float* __restrict__ Y, unsigned int* __restrict__ gh) {
    __shared__ unsigned int lh[4096];
    int b = blockIdx.y;
    for (int i = threadIdx.x; i < 4096; i += blockDim.x) lh[i] = 0u;
    __syncthreads();
    const float4* Y4 = (const float4*)(Y + (size_t)b * MTOT);
    int n4 = MTOT / 4;
    for (int i = blockIdx.x * blockDim.x + threadIdx.x; i < n4; i += gridDim.x * blockDim.x) {
        float4 v = Y4[i];
        atomicAdd(&lh[fmap(v.x) >> 20], 1u);
        atomicAdd(&lh[fmap(v.y) >> 20], 1u);
        atomicAdd(&lh[fmap(v.z) >> 20], 1u);
        atomicAdd(&lh[fmap(v.w) >> 20], 1u);
    }
    __syncthreads();
    unsigned int* h = gh + (size_t)b * 4096;
    for (int i = threadIdx.x; i < 4096; i += blockDim.x) {
        unsigned int c = lh[i];
        if (c) atomicAdd(&h[i], c);
    }
}

// ---- Descending scan over 4096 bins -> candidate bin + cumulative-above ----
__global__ void scan4096(const unsigned int* __restrict__ gh,
                         const unsigned int* __restrict__ baseIn,
                         unsigned int* __restrict__ candOut,
                         unsigned int* __restrict__ baseOut) {
    int b = blockIdx.x;
    const unsigned int* h = gh + (size_t)b * 4096;
    unsigned int prev = baseIn ? baseIn[b] : 0u;
    unsigned int target = RSEL - prev;
    __shared__ unsigned int psum[1024];
    int t = threadIdx.x;
    unsigned int c4[4];
    unsigned int s = 0;
    for (int k = 0; k < 4; k++) { c4[k] = h[4095 - (t * 4 + k)]; s += c4[k]; }
    psum[t] = s;
    __syncthreads();
    for (int off = 1; off < 1024; off <<= 1) {
        unsigned int v = (t >= off) ? psum[t - off] : 0u;
        __syncthreads();
        psum[t] += v;
        __syncthreads();
    }
    unsigned int incl = psum[t], excl = incl - s;
    if (excl < target && incl >= target) {
        unsigned int run = excl;
        for (int k = 0; k < 4; k++) {
            if (run + c4[k] >= target) {
                candOut[b] = (unsigned int)(4095 - (t * 4 + k));
                baseOut[b] = prev + run;
                break;
            }
            run += c4[k];
        }
    }
}

// ---- Pass 2: compact elements matching candidate top-12 prefix ----
__global__ void compact_kernel(const float* __restrict__ Y,
                               const unsigned int* __restrict__ cand1,
                               unsigned int* __restrict__ buf,
                               unsigned int* __restrict__ cnt) {
    int b = blockIdx.y;
    unsigned int cb = cand1[b];
    const float4* Y4 = (const float4*)(Y + (size_t)b * MTOT);
    unsigned int* bbuf = buf + (size_t)b * CAP;
    int n4 = MTOT / 4;
    for (int i = blockIdx.x * blockDim.x + threadIdx.x; i < n4; i += gridDim.x * blockDim.x) {
        float4 v = Y4[i];
        unsigned int u;
        u = fmap(v.x); if ((u >> 20) == cb) { unsigned int p = atomicAdd(&cnt[b], 1u); if (p < CAP) bbuf[p] = u; }
        u = fmap(v.y); if ((u >> 20) == cb) { unsigned int p = atomicAdd(&cnt[b], 1u); if (p < CAP) bbuf[p] = u; }
        u = fmap(v.z); if ((u >> 20) == cb) { unsigned int p = atomicAdd(&cnt[b], 1u); if (p < CAP) bbuf[p] = u; }
        u = fmap(v.w); if ((u >> 20) == cb) { unsigned int p = atomicAdd(&cnt[b], 1u); if (p < CAP) bbuf[p] = u; }
    }
}

// ---- Pass 3: mid-12-bit histogram over the (tiny) compacted buffer ----
__global__ void hist2_kernel(const unsigned int* __restrict__ buf,
                             const unsigned int* __restrict__ cnt,
                             unsigned int* __restrict__ gh) {
    int b = blockIdx.y;
    unsigned int n = cnt[b]; if (n > CAP) n = CAP;
    const unsigned int* bbuf = buf + (size_t)b * CAP;
    unsigned int* h = gh + (size_t)b * 4096;
    for (unsigned int i = blockIdx.x * blockDim.x + threadIdx.x; i < n; i += gridDim.x * blockDim.x)
        atomicAdd(&h[(bbuf[i] >> 8) & 0xFFFu], 1u);
}

// ---- Pass 4: low-8-bit histogram for elements matching 24-bit prefix ----
__global__ void hist3_kernel(const unsigned int* __restrict__ buf,
                             const unsigned int* __restrict__ cnt,
                             const unsigned int* __restrict__ cand2,
                             unsigned int* __restrict__ gh) {
    int b = blockIdx.y;
    unsigned int n = cnt[b]; if (n > CAP) n = CAP;
    unsigned int c2 = cand2[b];
    const unsigned int* bbuf = buf + (size_t)b * CAP;
    unsigned int* h = gh + (size_t)b * 256;
    for (unsigned int i = blockIdx.x * blockDim.x + threadIdx.x; i < n; i += gridDim.x * blockDim.x) {
        unsigned int u = bbuf[i];
        if (((u >> 8) & 0xFFFu) == c2) atomicAdd(&h[u & 0xFFu], 1u);
    }
}

// ---- Final scan over 256 bins -> exact threshold ----
__global__ void scan256(const unsigned int* __restrict__ gh,
                        const unsigned int* __restrict__ cand1,
                        const unsigned int* __restrict__ cand2,
                        const unsigned int* __restrict__ baseIn,
                        unsigned int* __restrict__ thr) {
    int b = blockIdx.x;
    const unsigned int* h = gh + (size_t)b * 256;
    unsigned int target = RSEL - baseIn[b];
    __shared__ unsigned int psum[256];
    int t = threadIdx.x;
    unsigned int s = h[255 - t];
    psum[t] = s;
    __syncthreads();
    for (int off = 1; off < 256; off <<= 1) {
        unsigned int v = (t >= off) ? psum[t - off] : 0u;
        __syncthreads();
        psum[t] += v;
        __syncthreads();
    }
    unsigned int incl = psum[t], excl = incl - s;
    if (excl < target && incl >= target)
        thr[b] = (cand1[b] << 20) | (cand2[b] << 8) | (unsigned int)(255 - t);
}

// ---- Threshold + NHWC->NCHW transpose. One thread = 4 pixels x 3 channels ----
__global__ void thresh_kernel(const float* __restrict__ Y,
                              const unsigned int* __restrict__ thr,
                              float* __restrict__ out) {
    int p = blockIdx.x * blockDim.x + threadIdx.x;   // [0, 8*1024*256)
    int w4 = p & 255;            // W/4 = 256
    int h  = (p >> 8) & 1023;
    int b  = p >> 18;
    unsigned int tu = thr[b];
    const float4* src = (const float4*)(Y + ((size_t)((b * HH + h) * WW) + (size_t)w4 * 4) * CC);
    float4 a0 = src[0], a1 = src[1], a2 = src[2];
    float4 r0, r1, r2;
    r0.x = (fmap(a0.x) >= tu) ? 1.f : 0.f;
    r0.y = (fmap(a0.w) >= tu) ? 1.f : 0.f;
    r0.z = (fmap(a1.z) >= tu) ? 1.f : 0.f;
    r0.w = (fmap(a2.y) >= tu) ? 1.f : 0.f;
    r1.x = (fmap(a0.y) >= tu) ? 1.f : 0.f;
    r1.y = (fmap(a1.x) >= tu) ? 1.f : 0.f;
    r1.z = (fmap(a1.w) >= tu) ? 1.f : 0.f;
    r1.w = (fmap(a2.z) >= tu) ? 1.f : 0.f;
    r2.x = (fmap(a0.z) >= tu) ? 1.f : 0.f;
    r2.y = (fmap(a1.y) >= tu) ? 1.f : 0.f;
    r2.z = (fmap(a2.x) >= tu) ? 1.f : 0.f;
    r2.w = (fmap(a2.w) >= tu) ? 1.f : 0.f;
    size_t base = ((size_t)(b * CC) * HH + h) * WW;
    ((float4*)(out + base))[w4]                        = r0;
    ((float4*)(out + base + (size_t)HH * WW))[w4]      = r1;
    ((float4*)(out + base + (size_t)2 * HH * WW))[w4]  = r2;
}

// ---- Z0 norm reduction: sum(abs^2) ----
__global__ void znorm_reduce(const float* __restrict__ zabs, float* __restrict__ acc) {
    int i = blockIdx.x * blockDim.x + threadIdx.x;   // over HH*WW/4 float4
    float s = 0.f;
    if (i < (HH * WW / 4)) {
        float4 v = ((const float4*)zabs)[i];
        s = v.x * v.x + v.y * v.y + v.z * v.z + v.w * v.w;
    }
    for (int off = 32; off > 0; off >>= 1) s += __shfl_down(s, off);
    __shared__ float ls[4];
    if ((threadIdx.x & 63) == 0) ls[threadIdx.x >> 6] = s;
    __syncthreads();
    if (threadIdx.x == 0) atomicAdd(acc, ls[0] + ls[1] + ls[2] + ls[3]);
}

// ---- Z0 write: interleaved complex64 (re,im) or real-only fallback ----
__global__ void zwrite_kernel(const float* __restrict__ zabs,
                              const float* __restrict__ zang,
                              const float* __restrict__ acc,
                              float* __restrict__ outz, int interleaved) {
    int i = blockIdx.x * blockDim.x + threadIdx.x;   // over HH*WW/2 pairs
    if (i >= HH * WW / 2) return;
    float inv = 1.0f / sqrtf(*acc);
    float2 a = ((const float2*)zabs)[i];
    float2 g = ((const float2*)zang)[i];
    float s0, c0, s1, c1;
    __sincosf(g.x, &s0, &c0);
    __sincosf(g.y, &s1, &c1);
    if (interleaved) {
        float4 o;
        o.x = a.x * c0 * inv; o.y = a.x * s0 * inv;
        o.z = a.y * c1 * inv; o.w = a.y * s1 * inv;
        ((float4*)outz)[i] = o;
    } else {
        float2 o;
        o.x = a.x * c0 * inv; o.y = a.y * c1 * inv;
        ((float2*)outz)[i] = o;
    }
}

extern "C" void kernel_launch(void* const* d_in, const int* in_sizes, int n_in,
                              void* d_out, int out_size, void* d_ws, size_t ws_size,
                              hipStream_t stream) {
    const float* Y    = (const float*)d_in[0];
    const float* zabs = (const float*)d_in[1];
    const float* zang = (const float*)d_in[2];
    float* out = (float*)d_out;

    unsigned char* ws = (unsigned char*)d_ws;
    unsigned int* gh1   = (unsigned int*)(ws + WS_GH1_OFF);
    unsigned int* gh2   = (unsigned int*)(ws + WS_GH2_OFF);
    unsigned int* gh3   = (unsigned int*)(ws + WS_GH3_OFF);
    unsigned int* cnt   = (unsigned int*)(ws + WS_CNT_OFF);
    unsigned int* cand1 = (unsigned int*)(ws + WS_CAND1_OFF);
    unsigned int* base1 = (unsigned int*)(ws + WS_BASE1_OFF);
    unsigned int* cand2 = (unsigned int*)(ws + WS_CAND2_OFF);
    unsigned int* base2 = (unsigned int*)(ws + WS_BASE2_OFF);
    unsigned int* thr   = (unsigned int*)(ws + WS_THR_OFF);
    float*        norm  = (float*)(ws + WS_NORM_OFF);
    unsigned int* buf   = (unsigned int*)(ws + WS_BUF_OFF);

    hipMemsetAsync(d_ws, 0, WS_ZERO_BYTES, stream);

    dim3 fullgrid(96, BATCH);
    hist1_kernel<<<fullgrid, 256, 0, stream>>>(Y, gh1);
    scan4096<<<BATCH, 1024, 0, stream>>>(gh1, nullptr, cand1, base1);
    compact_kernel<<<fullgrid, 256, 0, stream>>>(Y, cand1, buf, cnt);
    dim3 smallgrid(2, BATCH);
    hist2_kernel<<<smallgrid, 256, 0, stream>>>(buf, cnt, gh2);
    scan4096<<<BATCH, 1024, 0, stream>>>(gh2, base1, cand2, base2);
    hist3_kernel<<<smallgrid, 256, 0, stream>>>(buf, cnt, cand2, gh3);
    scan256<<<BATCH, 256, 0, stream>>>(gh3, cand1, cand2, base2, thr);

    // threshold + transpose: B*H*(W/4) = 2097152 threads
    thresh_kernel<<<(BATCH * HH * (WW / 4)) / 256, 256, 0, stream>>>(Y, thr, out);

    // Z0
    znorm_reduce<<<(HH * WW / 4) / 256, 256, 0, stream>>>(zabs, norm);
    size_t zoff = (size_t)BATCH * CC * HH * WW;   // 25165824
    int zfloats = out_size - (int)zoff;
    int interleaved = (zfloats >= 2 * HH * WW) ? 1 : 0;
    zwrite_kernel<<<(HH * WW / 2 + 255) / 256, 256, 0, stream>>>(
        zabs, zang, norm, out + zoff, interleaved);
}

// Round 3
// 254.306 us; speedup vs baseline: 10.6417x; 1.0037x over previous
//
#include <hip/hip_runtime.h>
#include <math.h>

#define BATCH 8
#define HH 1024
#define WW 1024
#define CC 3
#define MTOT (HH*WW*CC)          // 3145728 per batch
#define RSEL 1572864u            // ceil(M/2)
#define CAP  65536u              // compaction capacity per batch

// window: |x| < 2^-6  (median of 3.1M N(0,1) samples is within ~1e-3 of 0;
// window holds ~39K elems/batch; exact fallback below if it ever misses)
#define U_HI 0xBC800000u         // fmap(+2^-6)
#define U_LO 0x437FFFFFu         // fmap(-2^-6)

// ---- ws layout (bytes) ----
#define WS_CNT_OFF    0u         // 8 u32 : window counts
#define WS_CHI_OFF    64u        // 8 u32 : counts >= 2^-6
#define WS_THR_OFF    128u       // 8 u32 : final thresholds (u-space)
#define WS_NORM_OFF   192u       // 1 float
#define WS_ZERO_BYTES 256u
#define WS_BUF_OFF    1024u      // 8 * 64K u32 = 2 MB compacted values

__device__ __forceinline__ unsigned int fmap(float x) {
    unsigned int b = __float_as_uint(x);
    return (b & 0x80000000u) ? ~b : (b | 0x80000000u);
}

// ---- Pass 1 (fused): count x >= 2^-6 ; compact |x| < 2^-6 via LDS staging ----
__global__ void pass1_kernel(const float* __restrict__ Y,
                             unsigned int* __restrict__ buf,
                             unsigned int* __restrict__ cnt,
                             unsigned int* __restrict__ chigh) {
    __shared__ unsigned int lbuf[2048];
    __shared__ unsigned int lcnt;
    __shared__ unsigned int gbase;
    __shared__ unsigned int red[4];
    const int b = blockIdx.y;
    const int tid = threadIdx.x;
    if (tid == 0) lcnt = 0u;
    __syncthreads();

    const float4* Y4 = (const float4*)(Y + (size_t)b * MTOT);
    unsigned int* bbuf = buf + (size_t)b * CAP;
    const int n4 = MTOT / 4;
    const int stride = gridDim.x * blockDim.x;
    const int iters = (n4 + stride - 1) / stride;   // uniform across block
    unsigned int hcnt = 0u;

    for (int it = 0; it < iters; it++) {
        int i = it * stride + blockIdx.x * blockDim.x + tid;
        if (i < n4) {
            float4 v = Y4[i];
            unsigned int u;
#define PROC(comp) u = fmap(comp); \
            if (u >= U_HI) hcnt++; \
            else if (u >= U_LO) { unsigned int p = atomicAdd(&lcnt, 1u); if (p < 2048u) lbuf[p] = u; }
            PROC(v.x) PROC(v.y) PROC(v.z) PROC(v.w)
#undef PROC
        }
        __syncthreads();
        // flush when next iteration could overflow (max 1024 inserts/iter, lbuf=2048)
        if (lcnt >= 1024u) {
            unsigned int n = lcnt;                 // <= 2047 guaranteed
            if (tid == 0) gbase = atomicAdd(&cnt[b], n);
            __syncthreads();
            for (unsigned int j = tid; j < n; j += blockDim.x) {
                unsigned int p = gbase + j;
                if (p < CAP) bbuf[p] = lbuf[j];
            }
            __syncthreads();
            if (tid == 0) lcnt = 0u;
        }
        __syncthreads();
    }
    // final flush
    unsigned int n = lcnt;
    if (n > 2048u) n = 2048u;
    if (tid == 0 && n > 0u) gbase = atomicAdd(&cnt[b], n);
    __syncthreads();
    for (unsigned int j = tid; j < n; j += blockDim.x) {
        unsigned int p = gbase + j;
        if (p < CAP) bbuf[p] = lbuf[j];
    }
    // reduce high-count: wave shfl then one atomic per block
    for (int d = 32; d > 0; d >>= 1) hcnt += __shfl_down(hcnt, d);
    if ((tid & 63) == 0) red[tid >> 6] = hcnt;
    __syncthreads();
    if (tid == 0) atomicAdd(&chigh[b], red[0] + red[1] + red[2] + red[3]);
}

// ---- Refine: one block per batch; 3-level radix select (12/12/8 bits) ----
// Normal mode: select rank (R - chigh) in compacted buffer.
// Fallback mode (window missed / overflow): exact select over full batch data.
__global__ void __launch_bounds__(1024) refine_kernel(
        const float* __restrict__ Y,
        const unsigned int* __restrict__ buf,
        const unsigned int* __restrict__ cnt,
        const unsigned int* __restrict__ chigh,
        unsigned int* __restrict__ thr) {
    __shared__ unsigned int hist[4096];
    __shared__ unsigned int waveSums[16];
    __shared__ unsigned int selBin, selBase;
    __shared__ unsigned int mode_s, n_s, target_s;
    const int b = blockIdx.x;
    const int tid = threadIdx.x;
    const int lane = tid & 63, wid = tid >> 6;

    if (tid == 0) {
        unsigned int Nw = cnt[b], Ch = chigh[b];
        int fb = (Ch >= RSEL) || (Nw > CAP) || (Ch + Nw < RSEL);
        mode_s = (unsigned int)fb;
        n_s = fb ? (unsigned int)MTOT : Nw;
        target_s = fb ? RSEL : (RSEL - Ch);
    }
    __syncthreads();
    const int fb = (int)mode_s;
    const unsigned int n = n_s;
    unsigned int target = target_s;
    const unsigned int* src = buf + (size_t)b * CAP;
    const float* Yb = Y + (size_t)b * MTOT;

    unsigned int d1 = 0, d2 = 0;

    for (int level = 0; level < 3; level++) {
        const int nb  = (level < 2) ? 4096 : 256;
        const int bpt = (level < 2) ? 4 : 1;
        // zero hist
        for (int i = tid; i < nb; i += 1024) hist[i] = 0u;
        __syncthreads();
        // build hist over matching elements
        for (unsigned int i = tid; i < n; i += 1024u) {
            unsigned int u = fb ? fmap(Yb[i]) : src[i];
            if (level == 0) {
                atomicAdd(&hist[u >> 20], 1u);
            } else if (level == 1) {
                if ((u >> 20) == d1) atomicAdd(&hist[(u >> 8) & 0xFFFu], 1u);
            } else {
                if ((u >> 8) == ((d1 << 12) | d2)) atomicAdd(&hist[u & 0xFFu], 1u);
            }
        }
        __syncthreads();
        // descending scan + pick
        unsigned int c[4] = {0u, 0u, 0u, 0u};
        unsigned int s = 0u;
        const int nthr = nb / bpt;
        if (tid < nthr) {
            for (int k = 0; k < bpt; k++) { c[k] = hist[nb - 1 - (tid * bpt + k)]; s += c[k]; }
        }
        unsigned int incl = s;
        for (int d = 1; d < 64; d <<= 1) {
            unsigned int v = __shfl_up(incl, d);
            if (lane >= d) incl += v;
        }
        if (lane == 63) waveSums[wid] = incl;
        __syncthreads();
        if (tid < 16) {
            unsigned int w = waveSums[tid];
            for (int d = 1; d < 16; d <<= 1) {
                unsigned int v = __shfl_up(w, d);
                if (tid >= d) w += v;
            }
            waveSums[tid] = w;
        }
        __syncthreads();
        incl += (wid > 0) ? waveSums[wid - 1] : 0u;
        unsigned int excl = incl - s;
        if (s > 0u && excl < target && incl >= target) {
            unsigned int run = excl;
            for (int k = 0; k < bpt; k++) {
                if (run + c[k] >= target) {
                    selBin = (unsigned int)(nb - 1 - (tid * bpt + k));
                    selBase = run;
                    break;
                }
                run += c[k];
            }
        }
        __syncthreads();
        if (level == 0) d1 = selBin;
        else if (level == 1) d2 = selBin;
        target -= selBase;
        __syncthreads();
    }
    if (tid == 0) thr[b] = (d1 << 20) | (d2 << 8) | selBin;
}

// ---- Threshold + NHWC->NCHW transpose. One thread = 4 pixels x 3 channels ----
__global__ void thresh_kernel(const float* __restrict__ Y,
                              const unsigned int* __restrict__ thr,
                              float* __restrict__ out) {
    int p = blockIdx.x * blockDim.x + threadIdx.x;   // [0, 8*1024*256)
    int w4 = p & 255;            // W/4 = 256
    int h  = (p >> 8) & 1023;
    int b  = p >> 18;
    unsigned int tu = thr[b];
    const float4* src = (const float4*)(Y + ((size_t)((b * HH + h) * WW) + (size_t)w4 * 4) * CC);
    float4 a0 = src[0], a1 = src[1], a2 = src[2];
    float4 r0, r1, r2;
    r0.x = (fmap(a0.x) >= tu) ? 1.f : 0.f;
    r0.y = (fmap(a0.w) >= tu) ? 1.f : 0.f;
    r0.z = (fmap(a1.z) >= tu) ? 1.f : 0.f;
    r0.w = (fmap(a2.y) >= tu) ? 1.f : 0.f;
    r1.x = (fmap(a0.y) >= tu) ? 1.f : 0.f;
    r1.y = (fmap(a1.x) >= tu) ? 1.f : 0.f;
    r1.z = (fmap(a1.w) >= tu) ? 1.f : 0.f;
    r1.w = (fmap(a2.z) >= tu) ? 1.f : 0.f;
    r2.x = (fmap(a0.z) >= tu) ? 1.f : 0.f;
    r2.y = (fmap(a1.y) >= tu) ? 1.f : 0.f;
    r2.z = (fmap(a2.x) >= tu) ? 1.f : 0.f;
    r2.w = (fmap(a2.w) >= tu) ? 1.f : 0.f;
    size_t base = ((size_t)(b * CC) * HH + h) * WW;
    ((float4*)(out + base))[w4]                        = r0;
    ((float4*)(out + base + (size_t)HH * WW))[w4]      = r1;
    ((float4*)(out + base + (size_t)2 * HH * WW))[w4]  = r2;
}

// ---- Z0 norm reduction: sum(abs^2), one atomic per block ----
__global__ void znorm_reduce(const float* __restrict__ zabs, float* __restrict__ acc) {
    float s = 0.f;
    const int n4 = HH * WW / 4;
    for (int i = blockIdx.x * blockDim.x + threadIdx.x; i < n4; i += gridDim.x * blockDim.x) {
        float4 v = ((const float4*)zabs)[i];
        s += v.x * v.x + v.y * v.y + v.z * v.z + v.w * v.w;
    }
    for (int off = 32; off > 0; off >>= 1) s += __shfl_down(s, off);
    __shared__ float ls[4];
    if ((threadIdx.x & 63) == 0) ls[threadIdx.x >> 6] = s;
    __syncthreads();
    if (threadIdx.x == 0) atomicAdd(acc, ls[0] + ls[1] + ls[2] + ls[3]);
}

// ---- Z0 write: interleaved complex64 (re,im) or real-only fallback ----
__global__ void zwrite_kernel(const float* __restrict__ zabs,
                              const float* __restrict__ zang,
                              const float* __restrict__ acc,
                              float* __restrict__ outz, int interleaved) {
    int i = blockIdx.x * blockDim.x + threadIdx.x;   // over HH*WW/2 pairs
    if (i >= HH * WW / 2) return;
    float inv = 1.0f / sqrtf(*acc);
    float2 a = ((const float2*)zabs)[i];
    float2 g = ((const float2*)zang)[i];
    float s0, c0, s1, c1;
    __sincosf(g.x, &s0, &c0);
    __sincosf(g.y, &s1, &c1);
    if (interleaved) {
        float4 o;
        o.x = a.x * c0 * inv; o.y = a.x * s0 * inv;
        o.z = a.y * c1 * inv; o.w = a.y * s1 * inv;
        ((float4*)outz)[i] = o;
    } else {
        float2 o;
        o.x = a.x * c0 * inv; o.y = a.y * c1 * inv;
        ((float2*)outz)[i] = o;
    }
}

extern "C" void kernel_launch(void* const* d_in, const int* in_sizes, int n_in,
                              void* d_out, int out_size, void* d_ws, size_t ws_size,
                              hipStream_t stream) {
    const float* Y    = (const float*)d_in[0];
    const float* zabs = (const float*)d_in[1];
    const float* zang = (const float*)d_in[2];
    float* out = (float*)d_out;

    unsigned char* ws = (unsigned char*)d_ws;
    unsigned int* cnt   = (unsigned int*)(ws + WS_CNT_OFF);
    unsigned int* chigh = (unsigned int*)(ws + WS_CHI_OFF);
    unsigned int* thr   = (unsigned int*)(ws + WS_THR_OFF);
    float*        norm  = (float*)(ws + WS_NORM_OFF);
    unsigned int* buf   = (unsigned int*)(ws + WS_BUF_OFF);

    hipMemsetAsync(d_ws, 0, WS_ZERO_BYTES, stream);

    dim3 fullgrid(96, BATCH);
    pass1_kernel<<<fullgrid, 256, 0, stream>>>(Y, buf, cnt, chigh);
    refine_kernel<<<BATCH, 1024, 0, stream>>>(Y, buf, cnt, chigh, thr);

    // threshold + transpose: B*H*(W/4) = 2097152 threads
    thresh_kernel<<<(BATCH * HH * (WW / 4)) / 256, 256, 0, stream>>>(Y, thr, out);

    // Z0
    znorm_reduce<<<256, 256, 0, stream>>>(zabs, norm);
    size_t zoff = (size_t)BATCH * CC * HH * WW;   // 25165824
    int zfloats = out_size - (int)zoff;
    int interleaved = (zfloats >= 2 * HH * WW) ? 1 : 0;
    zwrite_kernel<<<(HH * WW / 2 + 255) / 256, 256, 0, stream>>>(
        zabs, zang, norm, out + zoff, interleaved);
}